// Round 1
// baseline (2489.984 us; speedup 1.0000x reference)
//
#include <hip/hip_runtime.h>
#include <hip/hip_cooperative_groups.h>
#include <math.h>

namespace cg = cooperative_groups;

// Shapes: B=2, D=64, L=512, H=1024
// ws layout (floats):
//   pF: [0, 131072)       pI: [131072, 262144)   pO: [262144, 393216)
//   stC: [393216, 397312) (2 parities x 2 x 1024)
//   stH: [397312, 401408)
// total 401408 floats = 1,605,632 bytes (memset to 0 each call)

__device__ __forceinline__ float sigf(float x)   { return 1.0f / (1.0f + __expf(-x)); }
__device__ __forceinline__ float geluf(float x)  { return 0.5f * x * (1.0f + erff(x * 0.70710678118654752f)); }
__device__ __forceinline__ float clampf(float x, float lo, float hi) { return fminf(fmaxf(x, lo), hi); }

// ---------------- Phase 1: pX[b,d,h] = sum_l trans[b,d,l,h] * tX[l] ----------------
// grid = 128 (b,d) * 8 l-chunks = 1024 blocks, 256 threads; thread owns float4 column t.
__global__ __launch_bounds__(256) void proj_kernel(
    const float* __restrict__ trans,
    const float* __restrict__ tF, const float* __restrict__ tI, const float* __restrict__ tO,
    float* __restrict__ pF, float* __restrict__ pI, float* __restrict__ pO)
{
    __shared__ float sF[64], sI[64], sO[64];
    const int t  = threadIdx.x;
    const int bd = blockIdx.x >> 3;
    const int l0 = (blockIdx.x & 7) * 64;
    if (t < 64)       sF[t]       = tF[l0 + t];
    else if (t < 128) sI[t - 64]  = tI[l0 + t - 64];
    else if (t < 192) sO[t - 128] = tO[l0 + t - 128];
    __syncthreads();

    const float4* tr = (const float4*)trans + ((size_t)bd * 512 + l0) * 256 + t;
    float4 aF = make_float4(0.f,0.f,0.f,0.f);
    float4 aI = make_float4(0.f,0.f,0.f,0.f);
    float4 aO = make_float4(0.f,0.f,0.f,0.f);
    #pragma unroll 4
    for (int l = 0; l < 64; ++l) {
        float4 v = tr[(size_t)l * 256];
        float wf = sF[l], wi = sI[l], wo = sO[l];
        aF.x = fmaf(v.x, wf, aF.x); aF.y = fmaf(v.y, wf, aF.y);
        aF.z = fmaf(v.z, wf, aF.z); aF.w = fmaf(v.w, wf, aF.w);
        aI.x = fmaf(v.x, wi, aI.x); aI.y = fmaf(v.y, wi, aI.y);
        aI.z = fmaf(v.z, wi, aI.z); aI.w = fmaf(v.w, wi, aI.w);
        aO.x = fmaf(v.x, wo, aO.x); aO.y = fmaf(v.y, wo, aO.y);
        aO.z = fmaf(v.z, wo, aO.z); aO.w = fmaf(v.w, wo, aO.w);
    }
    const int base = bd * 1024 + t * 4;
    atomicAdd(&pF[base + 0], aF.x); atomicAdd(&pF[base + 1], aF.y);
    atomicAdd(&pF[base + 2], aF.z); atomicAdd(&pF[base + 3], aF.w);
    atomicAdd(&pI[base + 0], aI.x); atomicAdd(&pI[base + 1], aI.y);
    atomicAdd(&pI[base + 2], aI.z); atomicAdd(&pI[base + 3], aI.w);
    atomicAdd(&pO[base + 0], aO.x); atomicAdd(&pO[base + 1], aO.y);
    atomicAdd(&pO[base + 2], aO.z); atomicAdd(&pO[base + 3], aO.w);
}

// ---------------- Phase 2: 64-step recurrence, cooperative persistent kernel ----------------
// 256 blocks x 256 threads (4 waves). Wave w of block B owns output row hrow = B*4+w.
// Weight rows (5 x 1024 floats = 20 float4/lane) live in registers for the whole kernel.
__global__ __launch_bounds__(256, 1) void recur_kernel(
    const float* __restrict__ pF, const float* __restrict__ pI, const float* __restrict__ pO,
    const float* __restrict__ Wf, const float* __restrict__ bf,
    const float* __restrict__ Wi, const float* __restrict__ bi,
    const float* __restrict__ Wg, const float* __restrict__ bg,
    const float* __restrict__ Wo, const float* __restrict__ bo,
    const float* __restrict__ Wp, const float* __restrict__ bp,
    const float* __restrict__ c_gamma, const float* __restrict__ c_beta,
    const float* __restrict__ h_gamma, const float* __restrict__ h_beta,
    const int* __restrict__ mask,
    float* __restrict__ stC, float* __restrict__ stH, float* __restrict__ out)
{
    cg::grid_group grid = cg::this_grid();
    const int t    = threadIdx.x;
    const int lane = t & 63;
    const int wv   = t >> 6;
    const int hrow = (blockIdx.x << 2) + wv;

    // register-resident weight rows
    float4 wfr[4], wir[4], wgr[4], wor[4], wpr[4];
    {
        const float4* rf = (const float4*)(Wf + (size_t)hrow * 1024);
        const float4* ri = (const float4*)(Wi + (size_t)hrow * 1024);
        const float4* rg = (const float4*)(Wg + (size_t)hrow * 1024);
        const float4* ro = (const float4*)(Wo + (size_t)hrow * 1024);
        const float4* rp = (const float4*)(Wp + (size_t)hrow * 1024);
        #pragma unroll
        for (int q = 0; q < 4; ++q) {
            const int k4 = lane + 64 * q;
            wfr[q] = rf[k4]; wir[q] = ri[k4]; wgr[q] = rg[k4];
            wor[q] = ro[k4]; wpr[q] = rp[k4];
        }
    }
    const float bfv = bf[hrow], biv = bi[hrow], bgv = bg[hrow], bov = bo[hrow], bpv = bp[hrow];

    // per-thread LN affine params for elements e = t + 256*j
    float cgv[4], cbv[4], hgv[4], hbv[4];
    #pragma unroll
    for (int j = 0; j < 4; ++j) {
        const int e = t + 256 * j;
        cgv[j] = c_gamma[e]; cbv[j] = c_beta[e];
        hgv[j] = h_gamma[e]; hbv[j] = h_beta[e];
    }

    __shared__ float nbuf[4][1024];   // nH0, nH1, nC0, nC1
    __shared__ float red[4][8];

    for (int d = 0; d < 64; ++d) {
        const int par = d & 1;
        const float* cc = stC + par * 2048;
        const float* hc = stH + par * 2048;
        float* cn = stC + (par ^ 1) * 2048;
        float* hn = stH + (par ^ 1) * 2048;

        // ---- LayerNorm stats (redundant per block) ----
        float cv0[4], cv1[4], hv0[4], hv1[4];
        float s0=0,s1=0,s2=0,s3=0,s4=0,s5=0,s6=0,s7=0;
        #pragma unroll
        for (int j = 0; j < 4; ++j) {
            const int e = t + 256 * j;
            cv0[j] = cc[e]; cv1[j] = cc[1024 + e];
            hv0[j] = hc[e]; hv1[j] = hc[1024 + e];
            s0 += cv0[j]; s1 += cv0[j]*cv0[j];
            s2 += cv1[j]; s3 += cv1[j]*cv1[j];
            s4 += hv0[j]; s5 += hv0[j]*hv0[j];
            s6 += hv1[j]; s7 += hv1[j]*hv1[j];
        }
        #pragma unroll
        for (int off = 32; off; off >>= 1) {
            s0 += __shfl_xor(s0, off); s1 += __shfl_xor(s1, off);
            s2 += __shfl_xor(s2, off); s3 += __shfl_xor(s3, off);
            s4 += __shfl_xor(s4, off); s5 += __shfl_xor(s5, off);
            s6 += __shfl_xor(s6, off); s7 += __shfl_xor(s7, off);
        }
        if (lane == 0) {
            red[wv][0]=s0; red[wv][1]=s1; red[wv][2]=s2; red[wv][3]=s3;
            red[wv][4]=s4; red[wv][5]=s5; red[wv][6]=s6; red[wv][7]=s7;
        }
        __syncthreads();
        const float tc0 = red[0][0]+red[1][0]+red[2][0]+red[3][0];
        const float qc0 = red[0][1]+red[1][1]+red[2][1]+red[3][1];
        const float tc1 = red[0][2]+red[1][2]+red[2][2]+red[3][2];
        const float qc1 = red[0][3]+red[1][3]+red[2][3]+red[3][3];
        const float th0 = red[0][4]+red[1][4]+red[2][4]+red[3][4];
        const float qh0 = red[0][5]+red[1][5]+red[2][5]+red[3][5];
        const float th1 = red[0][6]+red[1][6]+red[2][6]+red[3][6];
        const float qh1 = red[0][7]+red[1][7]+red[2][7]+red[3][7];
        const float inv = 1.0f / 1024.0f;
        const float mc0 = tc0*inv, rc0 = rsqrtf(qc0*inv - mc0*mc0 + 1e-5f);
        const float mc1 = tc1*inv, rc1 = rsqrtf(qc1*inv - mc1*mc1 + 1e-5f);
        const float mh0 = th0*inv, rh0 = rsqrtf(qh0*inv - mh0*mh0 + 1e-5f);
        const float mh1 = th1*inv, rh1 = rsqrtf(qh1*inv - mh1*mh1 + 1e-5f);

        #pragma unroll
        for (int j = 0; j < 4; ++j) {
            const int e = t + 256 * j;
            nbuf[0][e] = (hv0[j]-mh0)*rh0*hgv[j] + hbv[j];
            nbuf[1][e] = (hv1[j]-mh1)*rh1*hgv[j] + hbv[j];
            nbuf[2][e] = (cv0[j]-mc0)*rc0*cgv[j] + cbv[j];
            nbuf[3][e] = (cv1[j]-mc1)*rc1*cgv[j] + cbv[j];
        }
        __syncthreads();

        // ---- 10 dot products (5 matrices x b=0,1) for this wave's row ----
        float zf0=0,zf1=0,zi0=0,zi1=0,zg0=0,zg1=0,zo0=0,zo1=0,zp0=0,zp1=0;
        #pragma unroll
        for (int q = 0; q < 4; ++q) {
            const int k4 = lane + 64 * q;
            const float4 n0 = ((const float4*)nbuf[0])[k4];
            const float4 n1 = ((const float4*)nbuf[1])[k4];
            const float4 m0 = ((const float4*)nbuf[2])[k4];
            const float4 m1 = ((const float4*)nbuf[3])[k4];
            zf0 += wfr[q].x*n0.x + wfr[q].y*n0.y + wfr[q].z*n0.z + wfr[q].w*n0.w;
            zf1 += wfr[q].x*n1.x + wfr[q].y*n1.y + wfr[q].z*n1.z + wfr[q].w*n1.w;
            zi0 += wir[q].x*n0.x + wir[q].y*n0.y + wir[q].z*n0.z + wir[q].w*n0.w;
            zi1 += wir[q].x*n1.x + wir[q].y*n1.y + wir[q].z*n1.z + wir[q].w*n1.w;
            zg0 += wgr[q].x*n0.x + wgr[q].y*n0.y + wgr[q].z*n0.z + wgr[q].w*n0.w;
            zg1 += wgr[q].x*n1.x + wgr[q].y*n1.y + wgr[q].z*n1.z + wgr[q].w*n1.w;
            zo0 += wor[q].x*n0.x + wor[q].y*n0.y + wor[q].z*n0.z + wor[q].w*n0.w;
            zo1 += wor[q].x*n1.x + wor[q].y*n1.y + wor[q].z*n1.z + wor[q].w*n1.w;
            zp0 += wpr[q].x*m0.x + wpr[q].y*m0.y + wpr[q].z*m0.z + wpr[q].w*m0.w;
            zp1 += wpr[q].x*m1.x + wpr[q].y*m1.y + wpr[q].z*m1.z + wpr[q].w*m1.w;
        }
        #pragma unroll
        for (int off = 32; off; off >>= 1) {
            zf0 += __shfl_xor(zf0, off); zf1 += __shfl_xor(zf1, off);
            zi0 += __shfl_xor(zi0, off); zi1 += __shfl_xor(zi1, off);
            zg0 += __shfl_xor(zg0, off); zg1 += __shfl_xor(zg1, off);
            zo0 += __shfl_xor(zo0, off); zo1 += __shfl_xor(zo1, off);
            zp0 += __shfl_xor(zp0, off); zp1 += __shfl_xor(zp1, off);
        }

        // ---- gates + state update: lane 0 handles b=0, lane 1 handles b=1 ----
        if (lane < 2) {
            const int b = lane;
            const float zf = b ? zf1 : zf0;
            const float zi = b ? zi1 : zi0;
            const float zg = b ? zg1 : zg0;
            const float zo = b ? zo1 : zo0;
            const float zp = b ? zp1 : zp0;
            const int pidx = (b * 64 + d) * 1024 + hrow;
            const float pf = pF[pidx], pi = pI[pidx], po = pO[pidx];
            const float f  = sigf(clampf(zf + bfv, -8.f, 8.f) + pf);
            const float ig = sigf(clampf(zi + biv, -8.f, 8.f) + pi);
            const float g  = clampf(geluf(zg + bgv) + pi, -8.f, 8.f);
            const float o  = sigf(clampf(zo + bov, -8.f, 8.f) + po);
            const float hp = clampf(geluf(zp + bpv), -8.f, 8.f);
            const float co = cc[b * 1024 + hrow];
            const float ho = hc[b * 1024 + hrow];
            float c2 = co * f + ig * g;
            float h2 = o * hp;
            if (mask[b * 64 + d] == 0) { c2 = co; h2 = ho; }
            c2 = clampf(c2, -10.f, 10.f);
            h2 = clampf(h2, -10.f, 10.f);
            cn[b * 1024 + hrow] = c2;
            hn[b * 1024 + hrow] = h2;
            if (d == 63) out[b * 1024 + hrow] = h2;
        }
        grid.sync();
    }
}

extern "C" void kernel_launch(void* const* d_in, const int* in_sizes, int n_in,
                              void* d_out, int out_size, void* d_ws, size_t ws_size,
                              hipStream_t stream)
{
    const float* trans = (const float*)d_in[0];
    const int*   mask  = (const int*)d_in[1];
    const float* Wf = (const float*)d_in[2];  const float* bf = (const float*)d_in[3];
    const float* Wi = (const float*)d_in[4];  const float* bi = (const float*)d_in[5];
    const float* Wg = (const float*)d_in[6];  const float* bg = (const float*)d_in[7];
    const float* Wo = (const float*)d_in[8];  const float* bo = (const float*)d_in[9];
    const float* Wp = (const float*)d_in[10]; const float* bp = (const float*)d_in[11];
    const float* tF = (const float*)d_in[12];
    const float* tI = (const float*)d_in[13];
    const float* tO = (const float*)d_in[14];
    const float* c_gamma = (const float*)d_in[15];
    const float* c_beta  = (const float*)d_in[16];
    const float* h_gamma = (const float*)d_in[17];
    const float* h_beta  = (const float*)d_in[18];

    float* ws  = (float*)d_ws;
    float* pF  = ws;
    float* pI  = ws + 131072;
    float* pO  = ws + 262144;
    float* stC = ws + 393216;
    float* stH = ws + 397312;
    float* out = (float*)d_out;

    // zero pF/pI/pO (atomic accumulation targets) + initial c/h state
    hipMemsetAsync(d_ws, 0, 401408u * sizeof(float), stream);

    proj_kernel<<<dim3(1024), dim3(256), 0, stream>>>(trans, tF, tI, tO, pF, pI, pO);

    void* args[] = { &pF, &pI, &pO, &Wf, &bf, &Wi, &bi, &Wg, &bg, &Wo, &bo, &Wp, &bp,
                     &c_gamma, &c_beta, &h_gamma, &h_beta, &mask, &stC, &stH, &out };
    hipLaunchCooperativeKernel((void*)recur_kernel, dim3(256), dim3(256), args, 0, stream);
}

// Round 2
// 1608.352 us; speedup vs baseline: 1.5482x; 1.5482x over previous
//
#include <hip/hip_runtime.h>
#include <math.h>

// Shapes: B=2, D=64, L=512, H=1024
// ws layout (floats):
//   pF: [0, 131072)       pI: [131072, 262144)   pO: [262144, 393216)
//   stC: [393216, 397312) (2 parities x 2 x 1024)
//   stH: [397312, 401408)
//   cnt: [401408, 401472) (64 uint32 step counters)
// memset 401472 floats = 1,605,888 bytes each call

#define NBLK 256u

__device__ __forceinline__ float sigf(float x)   { return 1.0f / (1.0f + __expf(-x)); }
__device__ __forceinline__ float geluf(float x)  { return 0.5f * x * (1.0f + erff(x * 0.70710678118654752f)); }
__device__ __forceinline__ float clampf(float x, float lo, float hi) { return fminf(fmaxf(x, lo), hi); }

__device__ __forceinline__ void ast(float* p, float v) {
    __hip_atomic_store(p, v, __ATOMIC_RELAXED, __HIP_MEMORY_SCOPE_AGENT);
}
__device__ __forceinline__ float ald(const float* p) {
    return __hip_atomic_load(p, __ATOMIC_RELAXED, __HIP_MEMORY_SCOPE_AGENT);
}

// ---------------- Phase 1: pX[b,d,h] = sum_l trans[b,d,l,h] * tX[l] ----------------
__global__ __launch_bounds__(256) void proj_kernel(
    const float* __restrict__ trans,
    const float* __restrict__ tF, const float* __restrict__ tI, const float* __restrict__ tO,
    float* __restrict__ pF, float* __restrict__ pI, float* __restrict__ pO)
{
    __shared__ float sF[64], sI[64], sO[64];
    const int t  = threadIdx.x;
    const int bd = blockIdx.x >> 3;
    const int l0 = (blockIdx.x & 7) * 64;
    if (t < 64)       sF[t]       = tF[l0 + t];
    else if (t < 128) sI[t - 64]  = tI[l0 + t - 64];
    else if (t < 192) sO[t - 128] = tO[l0 + t - 128];
    __syncthreads();

    const float4* tr = (const float4*)trans + ((size_t)bd * 512 + l0) * 256 + t;
    float4 aF = make_float4(0.f,0.f,0.f,0.f);
    float4 aI = make_float4(0.f,0.f,0.f,0.f);
    float4 aO = make_float4(0.f,0.f,0.f,0.f);
    #pragma unroll 4
    for (int l = 0; l < 64; ++l) {
        float4 v = tr[(size_t)l * 256];
        float wf = sF[l], wi = sI[l], wo = sO[l];
        aF.x = fmaf(v.x, wf, aF.x); aF.y = fmaf(v.y, wf, aF.y);
        aF.z = fmaf(v.z, wf, aF.z); aF.w = fmaf(v.w, wf, aF.w);
        aI.x = fmaf(v.x, wi, aI.x); aI.y = fmaf(v.y, wi, aI.y);
        aI.z = fmaf(v.z, wi, aI.z); aI.w = fmaf(v.w, wi, aI.w);
        aO.x = fmaf(v.x, wo, aO.x); aO.y = fmaf(v.y, wo, aO.y);
        aO.z = fmaf(v.z, wo, aO.z); aO.w = fmaf(v.w, wo, aO.w);
    }
    const int base = bd * 1024 + t * 4;
    atomicAdd(&pF[base + 0], aF.x); atomicAdd(&pF[base + 1], aF.y);
    atomicAdd(&pF[base + 2], aF.z); atomicAdd(&pF[base + 3], aF.w);
    atomicAdd(&pI[base + 0], aI.x); atomicAdd(&pI[base + 1], aI.y);
    atomicAdd(&pI[base + 2], aI.z); atomicAdd(&pI[base + 3], aI.w);
    atomicAdd(&pO[base + 0], aO.x); atomicAdd(&pO[base + 1], aO.y);
    atomicAdd(&pO[base + 2], aO.z); atomicAdd(&pO[base + 3], aO.w);
}

// ---------------- Phase 2: 64-step recurrence, cooperative persistent kernel ----------------
// 256 blocks x 256 threads (4 waves). Wave wv of block B owns output row hrow = B*4+wv.
// Weight rows (5 x 1024 floats = 20 float4/lane) live in registers for the whole kernel.
// Cross-block state exchange via agent-scope atomics (bypass L1/L2 — no cache flush),
// custom counter barrier instead of cg::grid.sync() (which cost ~32 us/step).
__global__ __launch_bounds__(256, 1) void recur_kernel(
    const float* __restrict__ pF, const float* __restrict__ pI, const float* __restrict__ pO,
    const float* __restrict__ Wf, const float* __restrict__ bf,
    const float* __restrict__ Wi, const float* __restrict__ bi,
    const float* __restrict__ Wg, const float* __restrict__ bg,
    const float* __restrict__ Wo, const float* __restrict__ bo,
    const float* __restrict__ Wp, const float* __restrict__ bp,
    const float* __restrict__ c_gamma, const float* __restrict__ c_beta,
    const float* __restrict__ h_gamma, const float* __restrict__ h_beta,
    const int* __restrict__ mask,
    float* __restrict__ stC, float* __restrict__ stH,
    unsigned int* __restrict__ cnt, float* __restrict__ out)
{
    const int t    = threadIdx.x;
    const int lane = t & 63;
    const int wv   = t >> 6;
    const int hrow = (blockIdx.x << 2) + wv;

    // register-resident weight rows
    float4 wfr[4], wir[4], wgr[4], wor[4], wpr[4];
    {
        const float4* rf = (const float4*)(Wf + (size_t)hrow * 1024);
        const float4* ri = (const float4*)(Wi + (size_t)hrow * 1024);
        const float4* rg = (const float4*)(Wg + (size_t)hrow * 1024);
        const float4* ro = (const float4*)(Wo + (size_t)hrow * 1024);
        const float4* rp = (const float4*)(Wp + (size_t)hrow * 1024);
        #pragma unroll
        for (int q = 0; q < 4; ++q) {
            const int k4 = lane + 64 * q;
            wfr[q] = rf[k4]; wir[q] = ri[k4]; wgr[q] = rg[k4];
            wor[q] = ro[k4]; wpr[q] = rp[k4];
        }
    }
    const float bfv = bf[hrow], biv = bi[hrow], bgv = bg[hrow], bov = bo[hrow], bpv = bp[hrow];

    float cgv[4], cbv[4], hgv[4], hbv[4];
    #pragma unroll
    for (int j = 0; j < 4; ++j) {
        const int e = t + 256 * j;
        cgv[j] = c_gamma[e]; cbv[j] = c_beta[e];
        hgv[j] = h_gamma[e]; hbv[j] = h_beta[e];
    }

    __shared__ float nbuf[4][1024];   // nH0, nH1, nC0, nC1
    __shared__ float red[4][8];

    for (int d = 0; d < 64; ++d) {
        const int par = d & 1;
        const float* cc = stC + par * 2048;
        const float* hc = stH + par * 2048;
        float* cn = stC + (par ^ 1) * 2048;
        float* hn = stH + (par ^ 1) * 2048;

        // ---- state read (agent scope: coherence point, never stale) ----
        float cv0[4], cv1[4], hv0[4], hv1[4];
        float s0=0,s1=0,s2=0,s3=0,s4=0,s5=0,s6=0,s7=0;
        #pragma unroll
        for (int j = 0; j < 4; ++j) {
            const int e = t + 256 * j;
            cv0[j] = ald(cc + e);        cv1[j] = ald(cc + 1024 + e);
            hv0[j] = ald(hc + e);        hv1[j] = ald(hc + 1024 + e);
        }
        #pragma unroll
        for (int j = 0; j < 4; ++j) {
            s0 += cv0[j]; s1 += cv0[j]*cv0[j];
            s2 += cv1[j]; s3 += cv1[j]*cv1[j];
            s4 += hv0[j]; s5 += hv0[j]*hv0[j];
            s6 += hv1[j]; s7 += hv1[j]*hv1[j];
        }
        #pragma unroll
        for (int off = 32; off; off >>= 1) {
            s0 += __shfl_xor(s0, off); s1 += __shfl_xor(s1, off);
            s2 += __shfl_xor(s2, off); s3 += __shfl_xor(s3, off);
            s4 += __shfl_xor(s4, off); s5 += __shfl_xor(s5, off);
            s6 += __shfl_xor(s6, off); s7 += __shfl_xor(s7, off);
        }
        if (lane == 0) {
            red[wv][0]=s0; red[wv][1]=s1; red[wv][2]=s2; red[wv][3]=s3;
            red[wv][4]=s4; red[wv][5]=s5; red[wv][6]=s6; red[wv][7]=s7;
        }
        __syncthreads();
        const float tc0 = red[0][0]+red[1][0]+red[2][0]+red[3][0];
        const float qc0 = red[0][1]+red[1][1]+red[2][1]+red[3][1];
        const float tc1 = red[0][2]+red[1][2]+red[2][2]+red[3][2];
        const float qc1 = red[0][3]+red[1][3]+red[2][3]+red[3][3];
        const float th0 = red[0][4]+red[1][4]+red[2][4]+red[3][4];
        const float qh0 = red[0][5]+red[1][5]+red[2][5]+red[3][5];
        const float th1 = red[0][6]+red[1][6]+red[2][6]+red[3][6];
        const float qh1 = red[0][7]+red[1][7]+red[2][7]+red[3][7];
        const float inv = 1.0f / 1024.0f;
        const float mc0 = tc0*inv, rc0 = rsqrtf(qc0*inv - mc0*mc0 + 1e-5f);
        const float mc1 = tc1*inv, rc1 = rsqrtf(qc1*inv - mc1*mc1 + 1e-5f);
        const float mh0 = th0*inv, rh0 = rsqrtf(qh0*inv - mh0*mh0 + 1e-5f);
        const float mh1 = th1*inv, rh1 = rsqrtf(qh1*inv - mh1*mh1 + 1e-5f);

        #pragma unroll
        for (int j = 0; j < 4; ++j) {
            const int e = t + 256 * j;
            nbuf[0][e] = (hv0[j]-mh0)*rh0*hgv[j] + hbv[j];
            nbuf[1][e] = (hv1[j]-mh1)*rh1*hgv[j] + hbv[j];
            nbuf[2][e] = (cv0[j]-mc0)*rc0*cgv[j] + cbv[j];
            nbuf[3][e] = (cv1[j]-mc1)*rc1*cgv[j] + cbv[j];
        }
        __syncthreads();

        // ---- 10 dot products (5 matrices x b=0,1) for this wave's row ----
        float zf0=0,zf1=0,zi0=0,zi1=0,zg0=0,zg1=0,zo0=0,zo1=0,zp0=0,zp1=0;
        #pragma unroll
        for (int q = 0; q < 4; ++q) {
            const int k4 = lane + 64 * q;
            const float4 n0 = ((const float4*)nbuf[0])[k4];
            const float4 n1 = ((const float4*)nbuf[1])[k4];
            const float4 m0 = ((const float4*)nbuf[2])[k4];
            const float4 m1 = ((const float4*)nbuf[3])[k4];
            zf0 += wfr[q].x*n0.x + wfr[q].y*n0.y + wfr[q].z*n0.z + wfr[q].w*n0.w;
            zf1 += wfr[q].x*n1.x + wfr[q].y*n1.y + wfr[q].z*n1.z + wfr[q].w*n1.w;
            zi0 += wir[q].x*n0.x + wir[q].y*n0.y + wir[q].z*n0.z + wir[q].w*n0.w;
            zi1 += wir[q].x*n1.x + wir[q].y*n1.y + wir[q].z*n1.z + wir[q].w*n1.w;
            zg0 += wgr[q].x*n0.x + wgr[q].y*n0.y + wgr[q].z*n0.z + wgr[q].w*n0.w;
            zg1 += wgr[q].x*n1.x + wgr[q].y*n1.y + wgr[q].z*n1.z + wgr[q].w*n1.w;
            zo0 += wor[q].x*n0.x + wor[q].y*n0.y + wor[q].z*n0.z + wor[q].w*n0.w;
            zo1 += wor[q].x*n1.x + wor[q].y*n1.y + wor[q].z*n1.z + wor[q].w*n1.w;
            zp0 += wpr[q].x*m0.x + wpr[q].y*m0.y + wpr[q].z*m0.z + wpr[q].w*m0.w;
            zp1 += wpr[q].x*m1.x + wpr[q].y*m1.y + wpr[q].z*m1.z + wpr[q].w*m1.w;
        }
        #pragma unroll
        for (int off = 32; off; off >>= 1) {
            zf0 += __shfl_xor(zf0, off); zf1 += __shfl_xor(zf1, off);
            zi0 += __shfl_xor(zi0, off); zi1 += __shfl_xor(zi1, off);
            zg0 += __shfl_xor(zg0, off); zg1 += __shfl_xor(zg1, off);
            zo0 += __shfl_xor(zo0, off); zo1 += __shfl_xor(zo1, off);
            zp0 += __shfl_xor(zp0, off); zp1 += __shfl_xor(zp1, off);
        }

        // ---- gates + state update: lane 0 -> b=0, lane 1 -> b=1 ----
        if (lane < 2) {
            const int b = lane;
            const float zf = b ? zf1 : zf0;
            const float zi = b ? zi1 : zi0;
            const float zg = b ? zg1 : zg0;
            const float zo = b ? zo1 : zo0;
            const float zp = b ? zp1 : zp0;
            const int pidx = (b * 64 + d) * 1024 + hrow;
            const float pf = pF[pidx], pi = pI[pidx], po = pO[pidx];
            const float f  = sigf(clampf(zf + bfv, -8.f, 8.f) + pf);
            const float ig = sigf(clampf(zi + biv, -8.f, 8.f) + pi);
            const float g  = clampf(geluf(zg + bgv) + pi, -8.f, 8.f);
            const float o  = sigf(clampf(zo + bov, -8.f, 8.f) + po);
            const float hp = clampf(geluf(zp + bpv), -8.f, 8.f);
            const float co = ald(cc + b * 1024 + hrow);
            const float ho = ald(hc + b * 1024 + hrow);
            float c2 = co * f + ig * g;
            float h2 = o * hp;
            if (mask[b * 64 + d] == 0) { c2 = co; h2 = ho; }
            c2 = clampf(c2, -10.f, 10.f);
            h2 = clampf(h2, -10.f, 10.f);
            if (d == 63) {
                out[b * 1024 + hrow] = h2;
            } else {
                ast(cn + b * 1024 + hrow, c2);
                ast(hn + b * 1024 + hrow, h2);
            }
        }

        if (d == 63) break;   // no successor read — skip the barrier

        // ---- lightweight grid barrier: drain block stores, 1 atomic arrival, spin ----
        __syncthreads();      // emits s_waitcnt vmcnt(0) — all block stores at coherence point
        if (t == 0) {
            __hip_atomic_fetch_add(&cnt[d], 1u, __ATOMIC_ACQ_REL, __HIP_MEMORY_SCOPE_AGENT);
            while (__hip_atomic_load(&cnt[d], __ATOMIC_ACQUIRE, __HIP_MEMORY_SCOPE_AGENT) < NBLK)
                __builtin_amdgcn_s_sleep(1);
        }
        __syncthreads();
    }
}

extern "C" void kernel_launch(void* const* d_in, const int* in_sizes, int n_in,
                              void* d_out, int out_size, void* d_ws, size_t ws_size,
                              hipStream_t stream)
{
    const float* trans = (const float*)d_in[0];
    const int*   mask  = (const int*)d_in[1];
    const float* Wf = (const float*)d_in[2];  const float* bf = (const float*)d_in[3];
    const float* Wi = (const float*)d_in[4];  const float* bi = (const float*)d_in[5];
    const float* Wg = (const float*)d_in[6];  const float* bg = (const float*)d_in[7];
    const float* Wo = (const float*)d_in[8];  const float* bo = (const float*)d_in[9];
    const float* Wp = (const float*)d_in[10]; const float* bp = (const float*)d_in[11];
    const float* tF = (const float*)d_in[12];
    const float* tI = (const float*)d_in[13];
    const float* tO = (const float*)d_in[14];
    const float* c_gamma = (const float*)d_in[15];
    const float* c_beta  = (const float*)d_in[16];
    const float* h_gamma = (const float*)d_in[17];
    const float* h_beta  = (const float*)d_in[18];

    float* ws  = (float*)d_ws;
    float* pF  = ws;
    float* pI  = ws + 131072;
    float* pO  = ws + 262144;
    float* stC = ws + 393216;
    float* stH = ws + 397312;
    unsigned int* cnt = (unsigned int*)(ws + 401408);
    float* out = (float*)d_out;

    hipMemsetAsync(d_ws, 0, 401472u * sizeof(float), stream);

    proj_kernel<<<dim3(1024), dim3(256), 0, stream>>>(trans, tF, tI, tO, pF, pI, pO);

    void* args[] = { &pF, &pI, &pO, &Wf, &bf, &Wi, &bi, &Wg, &bg, &Wo, &bo, &Wp, &bp,
                     &c_gamma, &c_beta, &h_gamma, &h_beta, &mask, &stC, &stH, &cnt, &out };
    hipLaunchCooperativeKernel((void*)recur_kernel, dim3(256), dim3(256), args, 0, stream);
}

// Round 3
// 851.458 us; speedup vs baseline: 2.9244x; 1.8889x over previous
//
#include <hip/hip_runtime.h>
#include <math.h>

// Shapes: B=2, D=64, L=512, H=1024
// One fused cooperative kernel, 256 blocks x 256 threads (1 block/CU).
// Phase 1 (proj): block (bd = blk>>1, h-half = blk&1) computes pX[bd, h-half] for X in {F,I,O}.
//   1 MB coalesced trans reads per block, no atomics, no big memset.
// Phase 2 (recur): wave wv of block blk owns output row hrow = blk*4+wv; 5 weight rows
//   (80 VGPRs/lane) register-resident. Cross-block state via relaxed agent-scope atomics
//   (cache-bypassing, coherence-point). Grid barrier = flag-array + aggregator + release
//   (no RMW, no acquire/release cache-maintenance ops; ordering via __syncthreads vmcnt drain).
//
// ws layout (floats):
//   [0,256)        flags (uint, 1/block)
//   [256]          rel (uint)            (pad to 320)
//   [320, 4416)    stC (2 parities x 2 x 1024)
//   [4416, 8512)   stH
//   [8512, 139584) pF    [139584, 270656) pI    [270656, 401728) pO
// memset: first 8512 floats (34 KB) only.

#define NBLK 256

__device__ __forceinline__ float sigf(float x)   { return 1.0f / (1.0f + __expf(-x)); }
__device__ __forceinline__ float geluf(float x)  { return 0.5f * x * (1.0f + erff(x * 0.70710678118654752f)); }
__device__ __forceinline__ float clampf(float x, float lo, float hi) { return fminf(fmaxf(x, lo), hi); }

__device__ __forceinline__ void astf(float* p, float v) {
    __hip_atomic_store(p, v, __ATOMIC_RELAXED, __HIP_MEMORY_SCOPE_AGENT);
}
__device__ __forceinline__ float aldf(const float* p) {
    return __hip_atomic_load(p, __ATOMIC_RELAXED, __HIP_MEMORY_SCOPE_AGENT);
}
__device__ __forceinline__ void astu(unsigned* p, unsigned v) {
    __hip_atomic_store(p, v, __ATOMIC_RELAXED, __HIP_MEMORY_SCOPE_AGENT);
}
__device__ __forceinline__ unsigned aldu(const unsigned* p) {
    return __hip_atomic_load(p, __ATOMIC_RELAXED, __HIP_MEMORY_SCOPE_AGENT);
}

// Grid barrier: stores already drained by leading __syncthreads (vmcnt(0) before s_barrier).
__device__ __forceinline__ void gridbar(unsigned tgt, unsigned* flags, unsigned* rel,
                                        int blk, int t) {
    __syncthreads();                       // drains this block's agent stores to coherence point
    if (t == 0) astu(&flags[blk], tgt);
    if (blk == 0) {
        if (t < 64) {                      // aggregator wave: 4 flags per lane
            for (;;) {
                unsigned a = aldu(&flags[t]);
                unsigned b = aldu(&flags[t + 64]);
                unsigned c = aldu(&flags[t + 128]);
                unsigned d = aldu(&flags[t + 192]);
                int ok = (a >= tgt) && (b >= tgt) && (c >= tgt) && (d >= tgt);
                if (__all(ok)) break;
                __builtin_amdgcn_s_sleep(1);
            }
            if (t == 0) astu(rel, tgt);
        }
    } else if (t == 0) {
        while (aldu(rel) < tgt) __builtin_amdgcn_s_sleep(2);
    }
    __syncthreads();
}

__global__ __launch_bounds__(256, 1) void fused_kernel(
    const float* __restrict__ trans, const int* __restrict__ mask,
    const float* __restrict__ Wf, const float* __restrict__ bf,
    const float* __restrict__ Wi, const float* __restrict__ bi,
    const float* __restrict__ Wg, const float* __restrict__ bg,
    const float* __restrict__ Wo, const float* __restrict__ bo,
    const float* __restrict__ Wp, const float* __restrict__ bp,
    const float* __restrict__ tF, const float* __restrict__ tI, const float* __restrict__ tO,
    const float* __restrict__ c_gamma, const float* __restrict__ c_beta,
    const float* __restrict__ h_gamma, const float* __restrict__ h_beta,
    float* __restrict__ ws, float* __restrict__ out)
{
    const int t    = threadIdx.x;
    const int lane = t & 63;
    const int wv   = t >> 6;
    const int blk  = blockIdx.x;
    const int hrow = (blk << 2) + wv;

    unsigned* flags = (unsigned*)ws;
    unsigned* rel   = flags + 256;
    float* stC = ws + 320;
    float* stH = ws + 4416;
    float* pF  = ws + 8512;
    float* pI  = pF + 131072;
    float* pO  = pI + 131072;

    __shared__ float smem[4][1024];   // proj: sF/sI/sO + combine; recur: nbuf
    __shared__ float red[4][8];

    // ---- register-resident weight rows (issued early; latency overlaps proj) ----
    float4 wfr[4], wir[4], wgr[4], wor[4], wpr[4];
    {
        const float4* rf = (const float4*)(Wf + (size_t)hrow * 1024);
        const float4* ri = (const float4*)(Wi + (size_t)hrow * 1024);
        const float4* rg = (const float4*)(Wg + (size_t)hrow * 1024);
        const float4* ro = (const float4*)(Wo + (size_t)hrow * 1024);
        const float4* rp = (const float4*)(Wp + (size_t)hrow * 1024);
        #pragma unroll
        for (int q = 0; q < 4; ++q) {
            const int k4 = lane + 64 * q;
            wfr[q] = rf[k4]; wir[q] = ri[k4]; wgr[q] = rg[k4];
            wor[q] = ro[k4]; wpr[q] = rp[k4];
        }
    }
    const float bfv = bf[hrow], biv = bi[hrow], bgv = bg[hrow], bov = bo[hrow], bpv = bp[hrow];

    // ================= Phase 1: projections =================
    {
        float* sF = &smem[0][0];     // 512
        float* sI = &smem[0][512];   // 512
        float* sO = &smem[1][0];     // 512
        sF[t] = tF[t]; sF[t + 256] = tF[t + 256];
        sI[t] = tI[t]; sI[t + 256] = tI[t + 256];
        sO[t] = tO[t]; sO[t + 256] = tO[t + 256];
        __syncthreads();

        const int bd = blk >> 1;
        const int h0 = (blk & 1) * 512;
        const int s  = t & 127;          // float4 slot within the 512-wide half
        const int g  = t >> 7;           // l-parity group
        const float4* tr = (const float4*)trans + (size_t)bd * 512 * 256 + (h0 >> 2) + s;

        float4 aF = make_float4(0.f,0.f,0.f,0.f);
        float4 aI = make_float4(0.f,0.f,0.f,0.f);
        float4 aO = make_float4(0.f,0.f,0.f,0.f);
        #pragma unroll 8
        for (int li = 0; li < 256; ++li) {
            const int l = g + 2 * li;
            float4 v = tr[(size_t)l * 256];
            const float wf = sF[l], wi = sI[l], wo = sO[l];
            aF.x = fmaf(v.x, wf, aF.x); aF.y = fmaf(v.y, wf, aF.y);
            aF.z = fmaf(v.z, wf, aF.z); aF.w = fmaf(v.w, wf, aF.w);
            aI.x = fmaf(v.x, wi, aI.x); aI.y = fmaf(v.y, wi, aI.y);
            aI.z = fmaf(v.z, wi, aI.z); aI.w = fmaf(v.w, wi, aI.w);
            aO.x = fmaf(v.x, wo, aO.x); aO.y = fmaf(v.y, wo, aO.y);
            aO.z = fmaf(v.z, wo, aO.z); aO.w = fmaf(v.w, wo, aO.w);
        }
        float4* cmb = (float4*)&smem[2][0];   // 384 float4 in smem[2..3]
        if (g == 1) { cmb[s] = aF; cmb[128 + s] = aI; cmb[256 + s] = aO; }
        __syncthreads();
        if (g == 0) {
            const float4 bF = cmb[s], bI = cmb[128 + s], bO = cmb[256 + s];
            aF.x += bF.x; aF.y += bF.y; aF.z += bF.z; aF.w += bF.w;
            aI.x += bI.x; aI.y += bI.y; aI.z += bI.z; aI.w += bI.w;
            aO.x += bO.x; aO.y += bO.y; aO.z += bO.z; aO.w += bO.w;
            const int base = bd * 1024 + h0 + 4 * s;
            astf(&pF[base+0], aF.x); astf(&pF[base+1], aF.y);
            astf(&pF[base+2], aF.z); astf(&pF[base+3], aF.w);
            astf(&pI[base+0], aI.x); astf(&pI[base+1], aI.y);
            astf(&pI[base+2], aI.z); astf(&pI[base+3], aI.w);
            astf(&pO[base+0], aO.x); astf(&pO[base+1], aO.y);
            astf(&pO[base+2], aO.z); astf(&pO[base+3], aO.w);
        }
    }
    gridbar(1u, flags, rel, blk, t);

    // ================= Phase 2: recurrence =================
    float cgv[4], cbv[4], hgv[4], hbv[4];
    #pragma unroll
    for (int j = 0; j < 4; ++j) {
        const int e = t + 256 * j;
        cgv[j] = c_gamma[e]; cbv[j] = c_beta[e];
        hgv[j] = h_gamma[e]; hbv[j] = h_beta[e];
    }

    for (int d = 0; d < 64; ++d) {
        const int par = d & 1;
        const float* cc = stC + par * 2048;
        const float* hc = stH + par * 2048;
        float* cn = stC + (par ^ 1) * 2048;
        float* hn = stH + (par ^ 1) * 2048;

        // prefetch this step's projection scalars (hide MALL latency behind LN+dots)
        float pfv = 0.f, piv = 0.f, pov = 0.f;
        if (lane < 2) {
            const int pidx = (lane * 64 + d) * 1024 + hrow;
            pfv = aldf(&pF[pidx]); piv = aldf(&pI[pidx]); pov = aldf(&pO[pidx]);
        }

        // ---- state read (agent scope, coherence point) + LN stats ----
        float cv0[4], cv1[4], hv0[4], hv1[4];
        float s0=0,s1=0,s2=0,s3=0,s4=0,s5=0,s6=0,s7=0;
        #pragma unroll
        for (int j = 0; j < 4; ++j) {
            const int e = t + 256 * j;
            cv0[j] = aldf(cc + e);        cv1[j] = aldf(cc + 1024 + e);
            hv0[j] = aldf(hc + e);        hv1[j] = aldf(hc + 1024 + e);
        }
        #pragma unroll
        for (int j = 0; j < 4; ++j) {
            s0 += cv0[j]; s1 += cv0[j]*cv0[j];
            s2 += cv1[j]; s3 += cv1[j]*cv1[j];
            s4 += hv0[j]; s5 += hv0[j]*hv0[j];
            s6 += hv1[j]; s7 += hv1[j]*hv1[j];
        }
        #pragma unroll
        for (int off = 32; off; off >>= 1) {
            s0 += __shfl_xor(s0, off); s1 += __shfl_xor(s1, off);
            s2 += __shfl_xor(s2, off); s3 += __shfl_xor(s3, off);
            s4 += __shfl_xor(s4, off); s5 += __shfl_xor(s5, off);
            s6 += __shfl_xor(s6, off); s7 += __shfl_xor(s7, off);
        }
        if (lane == 0) {
            red[wv][0]=s0; red[wv][1]=s1; red[wv][2]=s2; red[wv][3]=s3;
            red[wv][4]=s4; red[wv][5]=s5; red[wv][6]=s6; red[wv][7]=s7;
        }
        __syncthreads();
        const float tc0 = red[0][0]+red[1][0]+red[2][0]+red[3][0];
        const float qc0 = red[0][1]+red[1][1]+red[2][1]+red[3][1];
        const float tc1 = red[0][2]+red[1][2]+red[2][2]+red[3][2];
        const float qc1 = red[0][3]+red[1][3]+red[2][3]+red[3][3];
        const float th0 = red[0][4]+red[1][4]+red[2][4]+red[3][4];
        const float qh0 = red[0][5]+red[1][5]+red[2][5]+red[3][5];
        const float th1 = red[0][6]+red[1][6]+red[2][6]+red[3][6];
        const float qh1 = red[0][7]+red[1][7]+red[2][7]+red[3][7];
        const float inv = 1.0f / 1024.0f;
        const float mc0 = tc0*inv, rc0 = rsqrtf(qc0*inv - mc0*mc0 + 1e-5f);
        const float mc1 = tc1*inv, rc1 = rsqrtf(qc1*inv - mc1*mc1 + 1e-5f);
        const float mh0 = th0*inv, rh0 = rsqrtf(qh0*inv - mh0*mh0 + 1e-5f);
        const float mh1 = th1*inv, rh1 = rsqrtf(qh1*inv - mh1*mh1 + 1e-5f);

        #pragma unroll
        for (int j = 0; j < 4; ++j) {
            const int e = t + 256 * j;
            smem[0][e] = (hv0[j]-mh0)*rh0*hgv[j] + hbv[j];
            smem[1][e] = (hv1[j]-mh1)*rh1*hgv[j] + hbv[j];
            smem[2][e] = (cv0[j]-mc0)*rc0*cgv[j] + cbv[j];
            smem[3][e] = (cv1[j]-mc1)*rc1*cgv[j] + cbv[j];
        }
        __syncthreads();

        // ---- 10 dot products (5 matrices x b=0,1) for this wave's row ----
        float zf0=0,zf1=0,zi0=0,zi1=0,zg0=0,zg1=0,zo0=0,zo1=0,zp0=0,zp1=0;
        #pragma unroll
        for (int q = 0; q < 4; ++q) {
            const int k4 = lane + 64 * q;
            const float4 n0 = ((const float4*)smem[0])[k4];
            const float4 n1 = ((const float4*)smem[1])[k4];
            const float4 m0 = ((const float4*)smem[2])[k4];
            const float4 m1 = ((const float4*)smem[3])[k4];
            zf0 += wfr[q].x*n0.x + wfr[q].y*n0.y + wfr[q].z*n0.z + wfr[q].w*n0.w;
            zf1 += wfr[q].x*n1.x + wfr[q].y*n1.y + wfr[q].z*n1.z + wfr[q].w*n1.w;
            zi0 += wir[q].x*n0.x + wir[q].y*n0.y + wir[q].z*n0.z + wir[q].w*n0.w;
            zi1 += wir[q].x*n1.x + wir[q].y*n1.y + wir[q].z*n1.z + wir[q].w*n1.w;
            zg0 += wgr[q].x*n0.x + wgr[q].y*n0.y + wgr[q].z*n0.z + wgr[q].w*n0.w;
            zg1 += wgr[q].x*n1.x + wgr[q].y*n1.y + wgr[q].z*n1.z + wgr[q].w*n1.w;
            zo0 += wor[q].x*n0.x + wor[q].y*n0.y + wor[q].z*n0.z + wor[q].w*n0.w;
            zo1 += wor[q].x*n1.x + wor[q].y*n1.y + wor[q].z*n1.z + wor[q].w*n1.w;
            zp0 += wpr[q].x*m0.x + wpr[q].y*m0.y + wpr[q].z*m0.z + wpr[q].w*m0.w;
            zp1 += wpr[q].x*m1.x + wpr[q].y*m1.y + wpr[q].z*m1.z + wpr[q].w*m1.w;
        }
        #pragma unroll
        for (int off = 32; off; off >>= 1) {
            zf0 += __shfl_xor(zf0, off); zf1 += __shfl_xor(zf1, off);
            zi0 += __shfl_xor(zi0, off); zi1 += __shfl_xor(zi1, off);
            zg0 += __shfl_xor(zg0, off); zg1 += __shfl_xor(zg1, off);
            zo0 += __shfl_xor(zo0, off); zo1 += __shfl_xor(zo1, off);
            zp0 += __shfl_xor(zp0, off); zp1 += __shfl_xor(zp1, off);
        }

        // ---- gates + state update: lane 0 -> b=0, lane 1 -> b=1 ----
        if (lane < 2) {
            const int b = lane;
            const float zf = b ? zf1 : zf0;
            const float zi = b ? zi1 : zi0;
            const float zg = b ? zg1 : zg0;
            const float zo = b ? zo1 : zo0;
            const float zp = b ? zp1 : zp0;
            const float f  = sigf(clampf(zf + bfv, -8.f, 8.f) + pfv);
            const float ig = sigf(clampf(zi + biv, -8.f, 8.f) + piv);
            const float g  = clampf(geluf(zg + bgv) + piv, -8.f, 8.f);
            const float o  = sigf(clampf(zo + bov, -8.f, 8.f) + pov);
            const float hp = clampf(geluf(zp + bpv), -8.f, 8.f);
            const float co = aldf(cc + b * 1024 + hrow);
            const float ho = aldf(hc + b * 1024 + hrow);
            float c2 = co * f + ig * g;
            float h2 = o * hp;
            if (mask[b * 64 + d] == 0) { c2 = co; h2 = ho; }
            c2 = clampf(c2, -10.f, 10.f);
            h2 = clampf(h2, -10.f, 10.f);
            if (d == 63) {
                out[b * 1024 + hrow] = h2;
            } else {
                astf(cn + b * 1024 + hrow, c2);
                astf(hn + b * 1024 + hrow, h2);
            }
        }

        if (d == 63) break;                 // no successor read — skip the barrier
        gridbar((unsigned)(d + 2), flags, rel, blk, t);
    }
}

extern "C" void kernel_launch(void* const* d_in, const int* in_sizes, int n_in,
                              void* d_out, int out_size, void* d_ws, size_t ws_size,
                              hipStream_t stream)
{
    const float* trans = (const float*)d_in[0];
    const int*   mask  = (const int*)d_in[1];
    const float* Wf = (const float*)d_in[2];  const float* bf = (const float*)d_in[3];
    const float* Wi = (const float*)d_in[4];  const float* bi = (const float*)d_in[5];
    const float* Wg = (const float*)d_in[6];  const float* bg = (const float*)d_in[7];
    const float* Wo = (const float*)d_in[8];  const float* bo = (const float*)d_in[9];
    const float* Wp = (const float*)d_in[10]; const float* bp = (const float*)d_in[11];
    const float* tF = (const float*)d_in[12];
    const float* tI = (const float*)d_in[13];
    const float* tO = (const float*)d_in[14];
    const float* c_gamma = (const float*)d_in[15];
    const float* c_beta  = (const float*)d_in[16];
    const float* h_gamma = (const float*)d_in[17];
    const float* h_beta  = (const float*)d_in[18];

    float* ws  = (float*)d_ws;
    float* out = (float*)d_out;

    // zero flags + rel + initial c/h state only (34 KB)
    hipMemsetAsync(d_ws, 0, 8512u * sizeof(float), stream);

    void* args[] = { (void*)&trans, (void*)&mask,
                     (void*)&Wf, (void*)&bf, (void*)&Wi, (void*)&bi,
                     (void*)&Wg, (void*)&bg, (void*)&Wo, (void*)&bo,
                     (void*)&Wp, (void*)&bp,
                     (void*)&tF, (void*)&tI, (void*)&tO,
                     (void*)&c_gamma, (void*)&c_beta, (void*)&h_gamma, (void*)&h_beta,
                     (void*)&ws, (void*)&out };
    hipLaunchCooperativeKernel((void*)fused_kernel, dim3(256), dim3(256), args, 0, stream);
}